// Round 22
// baseline (329.352 us; speedup 1.0000x reference)
//
#include <hip/hip_runtime.h>
#include <hip/hip_bf16.h>

#define B_ 4
#define H_ 16
#define L_ 2048
#define D_ 128
#define BH_ 64

typedef __attribute__((ext_vector_type(8))) _Float16 f16x8;
typedef __attribute__((ext_vector_type(4))) _Float16 f16x4;
typedef __attribute__((ext_vector_type(4))) float f32x4;
typedef __attribute__((ext_vector_type(2))) unsigned u32x2;

#define L2E 1.44269504088896f

// gm = L2E*gelu(v) + negm, tanh-form GELU (verified absmax-neutral, R15).
__device__ __forceinline__ float gelu_m(float v, float negm) {
  float u  = v * v;
  float m1 = 0.044715f * u;
  float w  = __builtin_fmaf(m1, v, v);
  float e  = __builtin_amdgcn_exp2f(-2.3020575f * w);
  float r  = __builtin_amdgcn_rcpf(1.0f + e);
  float t  = 1.44269504f * v;
  return __builtin_fmaf(t, r, negm);
}

__device__ __forceinline__ void gl2lds16(const void* g, void* l) {
  __builtin_amdgcn_global_load_lds(
      (const __attribute__((address_space(1))) void*)g,
      (__attribute__((address_space(3))) void*)l, 16, 0, 0);
}

__device__ __forceinline__ unsigned pkrtz(float a, float b) {
  auto t = __builtin_amdgcn_cvt_pkrtz(a, b);
  return __builtin_bit_cast(unsigned, t);
}

// ---------------------------------------------------------------------------
// Kernel 0: one-time W1,W2 f32 -> f16.
// ---------------------------------------------------------------------------
__global__ __launch_bounds__(256) void wcvt_kernel(
    const float* __restrict__ W1, const float* __restrict__ W2,
    _Float16* __restrict__ Wh1, _Float16* __restrict__ Wh2)
{
  int i = blockIdx.x * 256 + threadIdx.x;
  Wh1[i] = (_Float16)W1[i];
  Wh2[i] = (_Float16)W2[i];
}

// ---------------------------------------------------------------------------
// Kernel 1: q/k projections + x -> V^T (f16). R17/R19 keepers.
// ---------------------------------------------------------------------------
__global__ __launch_bounds__(256) void proj_tr_kernel(
    const float* __restrict__ x,
    const _Float16* __restrict__ Wh1, const float* __restrict__ b1,
    const _Float16* __restrict__ Wh2, const float* __restrict__ b2,
    _Float16* __restrict__ Qb, _Float16* __restrict__ Kb,
    _Float16* __restrict__ VT)
{
  const int tid  = threadIdx.x;
  const int wave = tid >> 6;
  const int lane = tid & 63;
  const int lhi  = lane >> 4;
  const int llo  = lane & 15;
  const int r0   = blockIdx.x * 64;
  const int wr0  = r0 + wave * 16;

  f16x8 a[4];
#pragma unroll
  for (int ks = 0; ks < 4; ++ks) {
    const f32x4* p = (const f32x4*)(x + (size_t)(wr0 + llo) * D_ + lhi * 8 + ks * 32);
    f32x4 f0 = p[0], f1 = p[1];
    union { unsigned u[4]; f16x8 v; } t;
    t.u[0] = pkrtz(f0[0], f0[1]);
    t.u[1] = pkrtz(f0[2], f0[3]);
    t.u[2] = pkrtz(f1[0], f1[1]);
    t.u[3] = pkrtz(f1[2], f1[3]);
    a[ks] = t.v;
  }

  f32x4 accq[8], acck[8];
#pragma unroll
  for (int n = 0; n < 8; ++n) {
    accq[n] = (f32x4){0.f, 0.f, 0.f, 0.f};
    acck[n] = (f32x4){0.f, 0.f, 0.f, 0.f};
  }

#pragma unroll
  for (int n = 0; n < 8; ++n) {
    const int e = n * 16 + llo;
#pragma unroll
    for (int ks = 0; ks < 4; ++ks) {
      f16x8 w1f = *(const f16x8*)(Wh1 + (size_t)e * D_ + lhi * 8 + ks * 32);
      f16x8 w2f = *(const f16x8*)(Wh2 + (size_t)e * D_ + lhi * 8 + ks * 32);
      accq[n] = __builtin_amdgcn_mfma_f32_16x16x32_f16(a[ks], w1f, accq[n], 0, 0, 0);
      acck[n] = __builtin_amdgcn_mfma_f32_16x16x32_f16(a[ks], w2f, acck[n], 0, 0, 0);
    }
  }

#pragma unroll
  for (int n = 0; n < 8; ++n) {
    const int e = n * 16 + llo;
    const float bias1 = b1[e];
    const float bias2 = b2[e];
#pragma unroll
    for (int r = 0; r < 4; ++r) {
      const size_t row = (size_t)wr0 + lhi * 4 + r;
      Qb[row * D_ + e] = (_Float16)(accq[n][r] + bias1);
      Kb[row * D_ + e] = (_Float16)(acck[n][r] + bias2);
    }
  }

  const int bh = r0 / L_;
  const int l0 = r0 % L_;
  const int d  = tid & 127;
  const int rh = tid >> 7;
  _Float16* dst = VT + (size_t)bh * D_ * L_ + (size_t)d * L_ + l0 + rh * 32;
#pragma unroll
  for (int j = 0; j < 4; ++j) {
    union { unsigned u[4]; f16x8 v; } t;
#pragma unroll
    for (int e = 0; e < 4; ++e) {
      float x0 = x[(size_t)(r0 + rh * 32 + j * 8 + 2 * e)     * D_ + d];
      float x1 = x[(size_t)(r0 + rh * 32 + j * 8 + 2 * e + 1) * D_ + d];
      t.u[e] = pkrtz(x0, x1);
    }
    *(f16x8*)(dst + j * 8) = t.v;
  }
}

// ---------------------------------------------------------------------------
// Kernel 2: fused gelu(QK^T)->softmax->@V, 16x16x32 MFMA OCCUPANCY BUILD.
// 8 waves x 16 q = 128 q/block, 1024 blocks. Per-wave state halves vs 32x32
// (qf 16 + sT 16 + p 16 + accO 32 AGPR ~ <=128 total -> 4 waves/SIMD), and
// LDS = K dbuf 32KB + V dbuf 32KB + wave-private P 16KB = 80KB -> 2 blk/CU
// (R3 measured 2 blocks at exactly this footprint). Index algebra = R1
// (verified): swapped QK^T puts q = lane&15; P via wave-private LDS (no
// barrier); R19 keepers: tanh gelu, speculative exp2, defer-max, deferred
// l-sum, both-sides XOR swizzles (K 4-bit, V/P 3-bit).
// ---------------------------------------------------------------------------
__global__ __launch_bounds__(512) void attn_kernel(
    const _Float16* __restrict__ Qb, const _Float16* __restrict__ Kb,
    const _Float16* __restrict__ VT, float* __restrict__ out)
{
  __shared__ _Float16 Ks[2][64 * 128];   // 2 x 16KB, K tile (64 k-rows)
  __shared__ _Float16 Vs[2][128 * 64];   // 2 x 16KB, V tile [128 d][64 k]
  __shared__ _Float16 Pl[8][1024];       // per-wave 16q x 64k P tile

  const int tid  = threadIdx.x;
  const int wave = tid >> 6;      // 0..7
  const int lane = tid & 63;
  const int lhi  = lane >> 4;
  const int llo  = lane & 15;

  // XCD swizzle: 1024 blocks, 8 XCDs -> 8 whole heads per XCD.
  const int bid = blockIdx.x;
  const int blk = (bid & 7) * 128 + (bid >> 3);
  const int bh  = blk >> 4;            // 16 q-blocks (128 rows) per head
  const int q0  = (blk & 15) * 128;
  const int b   = bh >> 4;
  const int h   = bh & 15;
  const int wq0 = q0 + wave * 16;

  const char* KheadB = (const char*)(Kb + (size_t)bh * L_ * D_);
  const char* VheadB = (const char*)(VT + (size_t)bh * D_ * L_);

  // ---- staging constants: K tile 16KB = 2 calls x 8KB; V same ----
  int kdst[2], ksrc[2], vdst[2], vsrc[2];
#pragma unroll
  for (int c = 0; c < 2; ++c) {
    {
      const int krow = c * 32 + wave * 4 + (lane >> 4);     // 0..63
      const int c0   = (lane & 15) * 8;                     // col halves
      kdst[c] = c * 8192 + wave * 1024;                     // wave-uniform
      ksrc[c] = krow * 256 + 2 * (c0 ^ ((krow & 15) << 3)); // 4-bit pre-swz
    }
    {
      const int vd = c * 64 + wave * 8 + (lane >> 3);       // d: 0..127
      const int c0 = (lane & 7) * 8;                        // col halves
      vdst[c] = c * 8192 + wave * 1024;
      vsrc[c] = vd * 4096 + 2 * (c0 ^ ((vd & 7) << 3));     // 3-bit pre-swz
    }
  }
  const int kswz = llo << 3;            // K read XOR (halves; row&15 = llo)
  const int vswz = (llo & 7) << 3;      // V/P read XOR (halves)
  const int pwb  = llo * 64 + lhi * 4;  // P write base (halves, pre-swz)

  // Q fragments (B-operand of swapped QK^T): j = llo = q-row, k = lhi*8+e
  f16x8 qf[4];
#pragma unroll
  for (int s = 0; s < 4; ++s)
    qf[s] = *(const f16x8*)(Qb + ((size_t)bh * L_ + wq0 + llo) * D_ + lhi * 8 + s * 32);

  f32x4 accO[8];
#pragma unroll
  for (int n = 0; n < 8; ++n) accO[n] = (f32x4){0.f, 0.f, 0.f, 0.f};
  float negm = 64.f;   // -m in exp2 units (synced across the 4 lanes per q)
  float l = 0.f;       // per-lane partial (16 of 64 k); reduced at epilogue

  _Float16* pw = Pl[wave];

  // ---- prologue: stage tile 0 ----
#pragma unroll
  for (int c = 0; c < 2; ++c) {
    gl2lds16(KheadB + ksrc[c], (char*)&Ks[0][0] + kdst[c]);
    gl2lds16(VheadB + vsrc[c], (char*)&Vs[0][0] + vdst[c]);
  }
  __syncthreads();

  for (int t = 0; t < L_ / 64; ++t) {      // 32 tiles, 1 barrier each
    const int cur = t & 1;
    if (t + 1 < L_ / 64) {
      const char* kt_ = KheadB + (size_t)(t + 1) * 16384;
      const char* vt_ = VheadB + (size_t)(t + 1) * 128;
#pragma unroll
      for (int c = 0; c < 2; ++c) {
        gl2lds16(kt_ + ksrc[c], (char*)&Ks[cur ^ 1][0] + kdst[c]);
        gl2lds16(vt_ + vsrc[c], (char*)&Vs[cur ^ 1][0] + vdst[c]);
      }
    }
    const _Float16* Kcur = &Ks[cur][0];
    const _Float16* Vcur = &Vs[cur][0];

    // ---- S^T = K Q^T: lane holds q=llo, k = js*16 + lhi*4 + r ----
    f32x4 s0 = {0.f,0.f,0.f,0.f}, s1 = {0.f,0.f,0.f,0.f};
    f32x4 s2 = {0.f,0.f,0.f,0.f}, s3 = {0.f,0.f,0.f,0.f};
    __builtin_amdgcn_s_setprio(1);
#pragma unroll
    for (int ks = 0; ks < 4; ++ks) {
      const int co = (lhi * 8 + ks * 32) ^ kswz;
      f16x8 k0 = *(const f16x8*)(Kcur + (0 * 16 + llo) * 128 + co);
      s0 = __builtin_amdgcn_mfma_f32_16x16x32_f16(k0, qf[ks], s0, 0, 0, 0);
      f16x8 k1 = *(const f16x8*)(Kcur + (1 * 16 + llo) * 128 + co);
      s1 = __builtin_amdgcn_mfma_f32_16x16x32_f16(k1, qf[ks], s1, 0, 0, 0);
      f16x8 k2 = *(const f16x8*)(Kcur + (2 * 16 + llo) * 128 + co);
      s2 = __builtin_amdgcn_mfma_f32_16x16x32_f16(k2, qf[ks], s2, 0, 0, 0);
      f16x8 k3 = *(const f16x8*)(Kcur + (3 * 16 + llo) * 128 + co);
      s3 = __builtin_amdgcn_mfma_f32_16x16x32_f16(k3, qf[ks], s3, 0, 0, 0);
    }
    __builtin_amdgcn_s_setprio(0);

    // ---- gelu (tanh form) with -m folded; speculative exp2 ----
    float gm[16];
#pragma unroll
    for (int r = 0; r < 4; ++r) {
      gm[0 + r]  = gelu_m(s0[r], negm);
      gm[4 + r]  = gelu_m(s1[r], negm);
      gm[8 + r]  = gelu_m(s2[r], negm);
      gm[12 + r] = gelu_m(s3[r], negm);
    }
    float p[16];
#pragma unroll
    for (int r = 0; r < 16; ++r) p[r] = __builtin_amdgcn_exp2f(gm[r]);

    float m0 = fmaxf(gm[0],  gm[1]),  m1 = fmaxf(gm[2],  gm[3]);
    float m2 = fmaxf(gm[4],  gm[5]),  m3 = fmaxf(gm[6],  gm[7]);
    float m4 = fmaxf(gm[8],  gm[9]),  m5 = fmaxf(gm[10], gm[11]);
    float m6 = fmaxf(gm[12], gm[13]), m7 = fmaxf(gm[14], gm[15]);
    float n0 = fmaxf(m0, m1), n1 = fmaxf(m2, m3);
    float n2 = fmaxf(m4, m5), n3 = fmaxf(m6, m7);
    float tm = fmaxf(fmaxf(n0, n1), fmaxf(n2, n3));
    tm = fmaxf(tm, __shfl_xor(tm, 16));
    tm = fmaxf(tm, __shfl_xor(tm, 32));   // negm synced across q's 4 lanes

    if (!__all(tm <= 11.5415603f)) {      // rare rescale path
      float dm = fmaxf(tm, 0.f);
      negm -= dm;
      float sc = __builtin_amdgcn_exp2f(-dm);
#pragma unroll
      for (int r = 0; r < 16; ++r) p[r] *= sc;
      l *= sc;
      float scr[4];
#pragma unroll
      for (int r = 0; r < 4; ++r) scr[r] = __shfl(sc, lhi * 4 + r);
#pragma unroll
      for (int n = 0; n < 8; ++n)
#pragma unroll
        for (int r = 0; r < 4; ++r) accO[n][r] *= scr[r];
    }

    float a0 = p[0]+p[1],   a1 = p[2]+p[3],   a2 = p[4]+p[5],   a3 = p[6]+p[7];
    float a4 = p[8]+p[9],   a5 = p[10]+p[11], a6 = p[12]+p[13], a7 = p[14]+p[15];
    l += ((a0+a1)+(a2+a3)) + ((a4+a5)+(a6+a7));

    // ---- P -> wave-private LDS (4x ds_write_b64, swizzled; R1-proven) ----
#pragma unroll
    for (int js = 0; js < 4; ++js) {
      union { unsigned u[2]; f16x4 v; } pj;
      pj.u[0] = pkrtz(p[js * 4 + 0], p[js * 4 + 1]);
      pj.u[1] = pkrtz(p[js * 4 + 2], p[js * 4 + 3]);
      *(f16x4*)(pw + ((pwb + js * 16) ^ vswz)) = pj.v;
    }

    // ---- O += P @ V (P from wave LDS, V from block LDS) ----
    __builtin_amdgcn_s_setprio(1);
#pragma unroll
    for (int ks2 = 0; ks2 < 2; ++ks2) {
      const int koff = lhi * 8 + ks2 * 32;
      f16x8 pf = *(const f16x8*)(pw + ((llo * 64 + koff) ^ vswz));
#pragma unroll
      for (int n = 0; n < 8; ++n) {
        f16x8 vf = *(const f16x8*)(Vcur + (n * 16 + llo) * 64 + (koff ^ vswz));
        accO[n] = __builtin_amdgcn_mfma_f32_16x16x32_f16(pf, vf, accO[n], 0, 0, 0);
      }
    }
    __builtin_amdgcn_s_setprio(0);

    __syncthreads();   // waves done with cur; prefetch into cur^1 landed
  }

  // ---- epilogue: reduce l across q's 4 lanes, then O/l ----
  l += __shfl_xor(l, 16);
  l += __shfl_xor(l, 32);
  float linv = __builtin_amdgcn_rcpf(l);
  float lb[4];
#pragma unroll
  for (int r = 0; r < 4; ++r) lb[r] = __shfl(linv, lhi * 4 + r);
#pragma unroll
  for (int n = 0; n < 8; ++n) {
    const int dcol = n * 16 + llo;
#pragma unroll
    for (int r = 0; r < 4; ++r) {
      const int i = wq0 + lhi * 4 + r;
      out[((size_t)(b * L_ + i) * H_ + h) * D_ + dcol] = accO[n][r] * lb[r];
    }
  }
}

extern "C" void kernel_launch(void* const* d_in, const int* in_sizes, int n_in,
                              void* d_out, int out_size, void* d_ws, size_t ws_size,
                              hipStream_t stream) {
  const float* x  = (const float*)d_in[0];
  const float* W1 = (const float*)d_in[1];
  const float* b1 = (const float*)d_in[2];
  const float* W2 = (const float*)d_in[3];
  const float* b2 = (const float*)d_in[4];
  float* out = (float*)d_out;

  const size_t N = (size_t)BH_ * L_ * D_;
  _Float16* Qb = (_Float16*)d_ws;
  _Float16* Kb = Qb + N;
  _Float16* VT = Kb + N;

  _Float16* Wh1 = (_Float16*)d_out;          // scratch; attn overwrites out
  _Float16* Wh2 = Wh1 + D_ * D_;

  wcvt_kernel<<<64, 256, 0, stream>>>(W1, W2, Wh1, Wh2);
  proj_tr_kernel<<<(BH_ * L_) / 64, 256, 0, stream>>>(x, Wh1, b1, Wh2, b2, Qb, Kb, VT);
  attn_kernel<<<BH_ * (L_ / 128), 512, 0, stream>>>(Qb, Kb, VT, out);
}

// Round 23
// 326.872 us; speedup vs baseline: 1.0076x; 1.0076x over previous
//
#include <hip/hip_runtime.h>
#include <hip/hip_bf16.h>

#define B_ 4
#define H_ 16
#define L_ 2048
#define D_ 128
#define BH_ 64

typedef __attribute__((ext_vector_type(8))) _Float16 f16x8;
typedef __attribute__((ext_vector_type(4))) _Float16 f16x4;
typedef __attribute__((ext_vector_type(4))) float f32x4;
typedef __attribute__((ext_vector_type(2))) unsigned u32x2;

#define L2E 1.44269504088896f

// gm = L2E*gelu(v) + negm, tanh-form GELU (verified absmax-neutral, R15).
__device__ __forceinline__ float gelu_m(float v, float negm) {
  float u  = v * v;
  float m1 = 0.044715f * u;
  float w  = __builtin_fmaf(m1, v, v);
  float e  = __builtin_amdgcn_exp2f(-2.3020575f * w);
  float r  = __builtin_amdgcn_rcpf(1.0f + e);
  float t  = 1.44269504f * v;
  return __builtin_fmaf(t, r, negm);
}

__device__ __forceinline__ void gl2lds16(const void* g, void* l) {
  __builtin_amdgcn_global_load_lds(
      (const __attribute__((address_space(1))) void*)g,
      (__attribute__((address_space(3))) void*)l, 16, 0, 0);
}

__device__ __forceinline__ unsigned pkrtz(float a, float b) {
  auto t = __builtin_amdgcn_cvt_pkrtz(a, b);
  return __builtin_bit_cast(unsigned, t);
}

// ---------------------------------------------------------------------------
// Kernel 0: one-time W1,W2 f32 -> f16.
// ---------------------------------------------------------------------------
__global__ __launch_bounds__(256) void wcvt_kernel(
    const float* __restrict__ W1, const float* __restrict__ W2,
    _Float16* __restrict__ Wh1, _Float16* __restrict__ Wh2)
{
  int i = blockIdx.x * 256 + threadIdx.x;
  Wh1[i] = (_Float16)W1[i];
  Wh2[i] = (_Float16)W2[i];
}

// ---------------------------------------------------------------------------
// Kernel 1: q/k projections + x -> V^T (f16). R17/R19 keepers.
// ---------------------------------------------------------------------------
__global__ __launch_bounds__(256) void proj_tr_kernel(
    const float* __restrict__ x,
    const _Float16* __restrict__ Wh1, const float* __restrict__ b1,
    const _Float16* __restrict__ Wh2, const float* __restrict__ b2,
    _Float16* __restrict__ Qb, _Float16* __restrict__ Kb,
    _Float16* __restrict__ VT)
{
  const int tid  = threadIdx.x;
  const int wave = tid >> 6;
  const int lane = tid & 63;
  const int lhi  = lane >> 4;
  const int llo  = lane & 15;
  const int r0   = blockIdx.x * 64;
  const int wr0  = r0 + wave * 16;

  f16x8 a[4];
#pragma unroll
  for (int ks = 0; ks < 4; ++ks) {
    const f32x4* p = (const f32x4*)(x + (size_t)(wr0 + llo) * D_ + lhi * 8 + ks * 32);
    f32x4 f0 = p[0], f1 = p[1];
    union { unsigned u[4]; f16x8 v; } t;
    t.u[0] = pkrtz(f0[0], f0[1]);
    t.u[1] = pkrtz(f0[2], f0[3]);
    t.u[2] = pkrtz(f1[0], f1[1]);
    t.u[3] = pkrtz(f1[2], f1[3]);
    a[ks] = t.v;
  }

  f32x4 accq[8], acck[8];
#pragma unroll
  for (int n = 0; n < 8; ++n) {
    accq[n] = (f32x4){0.f, 0.f, 0.f, 0.f};
    acck[n] = (f32x4){0.f, 0.f, 0.f, 0.f};
  }

#pragma unroll
  for (int n = 0; n < 8; ++n) {
    const int e = n * 16 + llo;
#pragma unroll
    for (int ks = 0; ks < 4; ++ks) {
      f16x8 w1f = *(const f16x8*)(Wh1 + (size_t)e * D_ + lhi * 8 + ks * 32);
      f16x8 w2f = *(const f16x8*)(Wh2 + (size_t)e * D_ + lhi * 8 + ks * 32);
      accq[n] = __builtin_amdgcn_mfma_f32_16x16x32_f16(a[ks], w1f, accq[n], 0, 0, 0);
      acck[n] = __builtin_amdgcn_mfma_f32_16x16x32_f16(a[ks], w2f, acck[n], 0, 0, 0);
    }
  }

#pragma unroll
  for (int n = 0; n < 8; ++n) {
    const int e = n * 16 + llo;
    const float bias1 = b1[e];
    const float bias2 = b2[e];
#pragma unroll
    for (int r = 0; r < 4; ++r) {
      const size_t row = (size_t)wr0 + lhi * 4 + r;
      Qb[row * D_ + e] = (_Float16)(accq[n][r] + bias1);
      Kb[row * D_ + e] = (_Float16)(acck[n][r] + bias2);
    }
  }

  const int bh = r0 / L_;
  const int l0 = r0 % L_;
  const int d  = tid & 127;
  const int rh = tid >> 7;
  _Float16* dst = VT + (size_t)bh * D_ * L_ + (size_t)d * L_ + l0 + rh * 32;
#pragma unroll
  for (int j = 0; j < 4; ++j) {
    union { unsigned u[4]; f16x8 v; } t;
#pragma unroll
    for (int e = 0; e < 4; ++e) {
      float x0 = x[(size_t)(r0 + rh * 32 + j * 8 + 2 * e)     * D_ + d];
      float x1 = x[(size_t)(r0 + rh * 32 + j * 8 + 2 * e + 1) * D_ + d];
      t.u[e] = pkrtz(x0, x1);
    }
    *(f16x8*)(dst + j * 8) = t.v;
  }
}

// ---------------------------------------------------------------------------
// Kernel 2: fused gelu(QK^T)->softmax->@V, 16x16x32 MFMA occupancy build
// (R22: VGPR 56, 2 blocks/CU, occupancy 40%, attn 243us).
// R23 delta: SHUFFLE-FREE defer guard -- __all(partial_tm <= THR) is exactly
// equivalent to __all(rowmax <= THR), so the common path (31/32 tiles) needs
// NO cross-lane shuffles; the rare rescale branch computes the true row max
// with the 2 shfl_xor there. Removes ~2x60-100cy DS latency per tile chain.
// ---------------------------------------------------------------------------
__global__ __launch_bounds__(512) void attn_kernel(
    const _Float16* __restrict__ Qb, const _Float16* __restrict__ Kb,
    const _Float16* __restrict__ VT, float* __restrict__ out)
{
  __shared__ _Float16 Ks[2][64 * 128];   // 2 x 16KB, K tile (64 k-rows)
  __shared__ _Float16 Vs[2][128 * 64];   // 2 x 16KB, V tile [128 d][64 k]
  __shared__ _Float16 Pl[8][1024];       // per-wave 16q x 64k P tile

  const int tid  = threadIdx.x;
  const int wave = tid >> 6;      // 0..7
  const int lane = tid & 63;
  const int lhi  = lane >> 4;
  const int llo  = lane & 15;

  // XCD swizzle: 1024 blocks, 8 XCDs -> 8 whole heads per XCD.
  const int bid = blockIdx.x;
  const int blk = (bid & 7) * 128 + (bid >> 3);
  const int bh  = blk >> 4;            // 16 q-blocks (128 rows) per head
  const int q0  = (blk & 15) * 128;
  const int b   = bh >> 4;
  const int h   = bh & 15;
  const int wq0 = q0 + wave * 16;

  const char* KheadB = (const char*)(Kb + (size_t)bh * L_ * D_);
  const char* VheadB = (const char*)(VT + (size_t)bh * D_ * L_);

  // ---- staging constants: K tile 16KB = 2 calls x 8KB; V same ----
  int kdst[2], ksrc[2], vdst[2], vsrc[2];
#pragma unroll
  for (int c = 0; c < 2; ++c) {
    {
      const int krow = c * 32 + wave * 4 + (lane >> 4);     // 0..63
      const int c0   = (lane & 15) * 8;                     // col halves
      kdst[c] = c * 8192 + wave * 1024;                     // wave-uniform
      ksrc[c] = krow * 256 + 2 * (c0 ^ ((krow & 15) << 3)); // 4-bit pre-swz
    }
    {
      const int vd = c * 64 + wave * 8 + (lane >> 3);       // d: 0..127
      const int c0 = (lane & 7) * 8;                        // col halves
      vdst[c] = c * 8192 + wave * 1024;
      vsrc[c] = vd * 4096 + 2 * (c0 ^ ((vd & 7) << 3));     // 3-bit pre-swz
    }
  }
  const int kswz = llo << 3;            // K read XOR (halves; row&15 = llo)
  const int vswz = (llo & 7) << 3;      // V/P read XOR (halves)
  const int pwb  = llo * 64 + lhi * 4;  // P write base (halves, pre-swz)

  // Q fragments (B-operand of swapped QK^T): j = llo = q-row, k = lhi*8+e
  f16x8 qf[4];
#pragma unroll
  for (int s = 0; s < 4; ++s)
    qf[s] = *(const f16x8*)(Qb + ((size_t)bh * L_ + wq0 + llo) * D_ + lhi * 8 + s * 32);

  f32x4 accO[8];
#pragma unroll
  for (int n = 0; n < 8; ++n) accO[n] = (f32x4){0.f, 0.f, 0.f, 0.f};
  float negm = 64.f;   // -m in exp2 units (uniform; updated only on rescale)
  float l = 0.f;       // per-lane partial (16 of 64 k); reduced at epilogue

  _Float16* pw = Pl[wave];

  // ---- prologue: stage tile 0 ----
#pragma unroll
  for (int c = 0; c < 2; ++c) {
    gl2lds16(KheadB + ksrc[c], (char*)&Ks[0][0] + kdst[c]);
    gl2lds16(VheadB + vsrc[c], (char*)&Vs[0][0] + vdst[c]);
  }
  __syncthreads();

  for (int t = 0; t < L_ / 64; ++t) {      // 32 tiles, 1 barrier each
    const int cur = t & 1;
    if (t + 1 < L_ / 64) {
      const char* kt_ = KheadB + (size_t)(t + 1) * 16384;
      const char* vt_ = VheadB + (size_t)(t + 1) * 128;
#pragma unroll
      for (int c = 0; c < 2; ++c) {
        gl2lds16(kt_ + ksrc[c], (char*)&Ks[cur ^ 1][0] + kdst[c]);
        gl2lds16(vt_ + vsrc[c], (char*)&Vs[cur ^ 1][0] + vdst[c]);
      }
    }
    const _Float16* Kcur = &Ks[cur][0];
    const _Float16* Vcur = &Vs[cur][0];

    // ---- S^T = K Q^T: lane holds q=llo, k = js*16 + lhi*4 + r ----
    f32x4 s0 = {0.f,0.f,0.f,0.f}, s1 = {0.f,0.f,0.f,0.f};
    f32x4 s2 = {0.f,0.f,0.f,0.f}, s3 = {0.f,0.f,0.f,0.f};
    __builtin_amdgcn_s_setprio(1);
#pragma unroll
    for (int ks = 0; ks < 4; ++ks) {
      const int co = (lhi * 8 + ks * 32) ^ kswz;
      f16x8 k0 = *(const f16x8*)(Kcur + (0 * 16 + llo) * 128 + co);
      s0 = __builtin_amdgcn_mfma_f32_16x16x32_f16(k0, qf[ks], s0, 0, 0, 0);
      f16x8 k1 = *(const f16x8*)(Kcur + (1 * 16 + llo) * 128 + co);
      s1 = __builtin_amdgcn_mfma_f32_16x16x32_f16(k1, qf[ks], s1, 0, 0, 0);
      f16x8 k2 = *(const f16x8*)(Kcur + (2 * 16 + llo) * 128 + co);
      s2 = __builtin_amdgcn_mfma_f32_16x16x32_f16(k2, qf[ks], s2, 0, 0, 0);
      f16x8 k3 = *(const f16x8*)(Kcur + (3 * 16 + llo) * 128 + co);
      s3 = __builtin_amdgcn_mfma_f32_16x16x32_f16(k3, qf[ks], s3, 0, 0, 0);
    }
    __builtin_amdgcn_s_setprio(0);

    // ---- gelu (tanh form) with -m folded; speculative exp2 ----
    float gm[16];
#pragma unroll
    for (int r = 0; r < 4; ++r) {
      gm[0 + r]  = gelu_m(s0[r], negm);
      gm[4 + r]  = gelu_m(s1[r], negm);
      gm[8 + r]  = gelu_m(s2[r], negm);
      gm[12 + r] = gelu_m(s3[r], negm);
    }
    float p[16];
#pragma unroll
    for (int r = 0; r < 16; ++r) p[r] = __builtin_amdgcn_exp2f(gm[r]);

    // per-lane partial max only; NO shuffles in the common path.
    float m0 = fmaxf(gm[0],  gm[1]),  m1 = fmaxf(gm[2],  gm[3]);
    float m2 = fmaxf(gm[4],  gm[5]),  m3 = fmaxf(gm[6],  gm[7]);
    float m4 = fmaxf(gm[8],  gm[9]),  m5 = fmaxf(gm[10], gm[11]);
    float m6 = fmaxf(gm[12], gm[13]), m7 = fmaxf(gm[14], gm[15]);
    float n0 = fmaxf(m0, m1), n1 = fmaxf(m2, m3);
    float n2 = fmaxf(m4, m5), n3 = fmaxf(m6, m7);
    float tm = fmaxf(fmaxf(n0, n1), fmaxf(n2, n3));

    // __all(partial <= THR) <=> __all(rowmax <= THR): shuffle-free guard.
    if (!__all(tm <= 11.5415603f)) {      // rare rescale path (~1/32)
      tm = fmaxf(tm, __shfl_xor(tm, 16)); // true row max, only here
      tm = fmaxf(tm, __shfl_xor(tm, 32));
      float dm = fmaxf(tm, 0.f);
      negm -= dm;
      float sc = __builtin_amdgcn_exp2f(-dm);
#pragma unroll
      for (int r = 0; r < 16; ++r) p[r] *= sc;
      l *= sc;
      float scr[4];
#pragma unroll
      for (int r = 0; r < 4; ++r) scr[r] = __shfl(sc, lhi * 4 + r);
#pragma unroll
      for (int n = 0; n < 8; ++n)
#pragma unroll
        for (int r = 0; r < 4; ++r) accO[n][r] *= scr[r];
    }

    float a0 = p[0]+p[1],   a1 = p[2]+p[3],   a2 = p[4]+p[5],   a3 = p[6]+p[7];
    float a4 = p[8]+p[9],   a5 = p[10]+p[11], a6 = p[12]+p[13], a7 = p[14]+p[15];
    l += ((a0+a1)+(a2+a3)) + ((a4+a5)+(a6+a7));

    // ---- P -> wave-private LDS (4x ds_write_b64, swizzled) ----
#pragma unroll
    for (int js = 0; js < 4; ++js) {
      union { unsigned u[2]; f16x4 v; } pj;
      pj.u[0] = pkrtz(p[js * 4 + 0], p[js * 4 + 1]);
      pj.u[1] = pkrtz(p[js * 4 + 2], p[js * 4 + 3]);
      *(f16x4*)(pw + ((pwb + js * 16) ^ vswz)) = pj.v;
    }

    // ---- O += P @ V (P from wave LDS, V from block LDS) ----
    __builtin_amdgcn_s_setprio(1);
#pragma unroll
    for (int ks2 = 0; ks2 < 2; ++ks2) {
      const int koff = lhi * 8 + ks2 * 32;
      f16x8 pf = *(const f16x8*)(pw + ((llo * 64 + koff) ^ vswz));
#pragma unroll
      for (int n = 0; n < 8; ++n) {
        f16x8 vf = *(const f16x8*)(Vcur + (n * 16 + llo) * 64 + (koff ^ vswz));
        accO[n] = __builtin_amdgcn_mfma_f32_16x16x32_f16(pf, vf, accO[n], 0, 0, 0);
      }
    }
    __builtin_amdgcn_s_setprio(0);

    __syncthreads();   // waves done with cur; prefetch into cur^1 landed
  }

  // ---- epilogue: reduce l across q's 4 lanes, then O/l ----
  l += __shfl_xor(l, 16);
  l += __shfl_xor(l, 32);
  float linv = __builtin_amdgcn_rcpf(l);
  float lb[4];
#pragma unroll
  for (int r = 0; r < 4; ++r) lb[r] = __shfl(linv, lhi * 4 + r);
#pragma unroll
  for (int n = 0; n < 8; ++n) {
    const int dcol = n * 16 + llo;
#pragma unroll
    for (int r = 0; r < 4; ++r) {
      const int i = wq0 + lhi * 4 + r;
      out[((size_t)(b * L_ + i) * H_ + h) * D_ + dcol] = accO[n][r] * lb[r];
    }
  }
}

extern "C" void kernel_launch(void* const* d_in, const int* in_sizes, int n_in,
                              void* d_out, int out_size, void* d_ws, size_t ws_size,
                              hipStream_t stream) {
  const float* x  = (const float*)d_in[0];
  const float* W1 = (const float*)d_in[1];
  const float* b1 = (const float*)d_in[2];
  const float* W2 = (const float*)d_in[3];
  const float* b2 = (const float*)d_in[4];
  float* out = (float*)d_out;

  const size_t N = (size_t)BH_ * L_ * D_;
  _Float16* Qb = (_Float16*)d_ws;
  _Float16* Kb = Qb + N;
  _Float16* VT = Kb + N;

  _Float16* Wh1 = (_Float16*)d_out;          // scratch; attn overwrites out
  _Float16* Wh2 = Wh1 + D_ * D_;

  wcvt_kernel<<<64, 256, 0, stream>>>(W1, W2, Wh1, Wh2);
  proj_tr_kernel<<<(BH_ * L_) / 64, 256, 0, stream>>>(x, Wh1, b1, Wh2, b2, Qb, Kb, VT);
  attn_kernel<<<BH_ * (L_ / 128), 512, 0, stream>>>(Qb, Kb, VT, out);
}